// Round 9
// baseline (10864.356 us; speedup 1.0000x reference)
//
#include <hip/hip_runtime.h>
#include <hip/hip_bf16.h>
#include <stdint.h>

typedef float f32x4 __attribute__((ext_vector_type(4)));
typedef float f32x16 __attribute__((ext_vector_type(16)));
typedef short bf16x8 __attribute__((ext_vector_type(8)));

#define LDW 1024
#define BATCH_SH 20  // 1<<20 elements per 1024x1024 matrix

__device__ __forceinline__ float b2f(__hip_bfloat16 h) { return __bfloat162float(h); }
__device__ __forceinline__ __hip_bfloat16 f2b(float f) { return __float2bfloat16(f); }

__device__ __forceinline__ void gload16(const void* g, void* l) {
  __builtin_amdgcn_global_load_lds((const __attribute__((address_space(1))) void*)g,
                                   (__attribute__((address_space(3))) void*)l,
                                   16, 0, 0);
}

// ---------------- Frobenius norm (2-stage) ----------------
__global__ void k_partial(const float* __restrict__ xin, float* __restrict__ partials) {
  const int b = blockIdx.y, ch = blockIdx.x, t = threadIdx.x;
  const size_t base = ((size_t)b << BATCH_SH) + (size_t)ch * 16384;
  float s = 0.f;
#pragma unroll
  for (int i = 0; i < 16; ++i) {
    f32x4 v = *reinterpret_cast<const f32x4*>(xin + base + (size_t)(i * 256 + t) * 4);
    s += v[0] * v[0] + v[1] * v[1] + v[2] * v[2] + v[3] * v[3];
  }
#pragma unroll
  for (int off = 32; off; off >>= 1) s += __shfl_down(s, off);
  __shared__ float red[4];
  if ((t & 63) == 0) red[t >> 6] = s;
  __syncthreads();
  if (t == 0) partials[b * 64 + ch] = red[0] + red[1] + red[2] + red[3];
}

__global__ void k_scale(const float* __restrict__ partials, float* __restrict__ scales) {
  const int b = blockIdx.x, t = threadIdx.x;
  float s = partials[b * 64 + t];
#pragma unroll
  for (int off = 32; off; off >>= 1) s += __shfl_down(s, off);
  if (t == 0) scales[b] = 1.1f / sqrtf(s);
}

// ---------------- scale + split + transpose-split ----------------
__global__ void k_scalesplit(const float* __restrict__ xin, const float* __restrict__ scales,
                             __hip_bfloat16* __restrict__ Xh, __hip_bfloat16* __restrict__ Xl,
                             __hip_bfloat16* __restrict__ XTh, __hip_bfloat16* __restrict__ XTl) {
  __shared__ float tile[64][65];
  const int b = blockIdx.z, tm = blockIdx.y, tn = blockIdx.x;
  const size_t boff = (size_t)b << BATCH_SH;
  const float s = scales[b];
  const int t = threadIdx.x, lr0 = t >> 6, lc = t & 63;
#pragma unroll
  for (int p = 0; p < 16; ++p) {
    const int lr = p * 4 + lr0;
    const size_t idx = boff + (size_t)(tm * 64 + lr) * LDW + tn * 64 + lc;
    const float v = xin[idx] * s;
    __hip_bfloat16 h = f2b(v);
    Xh[idx] = h;
    Xl[idx] = f2b(v - b2f(h));
    tile[lr][lc] = v;
  }
  __syncthreads();
#pragma unroll
  for (int p = 0; p < 16; ++p) {
    const int lr = p * 4 + lr0;
    const float v = tile[lc][lr];
    const size_t idx = boff + (size_t)(tn * 64 + lr) * LDW + tm * 64 + lc;
    __hip_bfloat16 h = f2b(v);
    XTh[idx] = h;
    XTl[idx] = f2b(v - b2f(h));
  }
}

// ---------------- split-bf16 GEMM: C = PA * PB^T, 256x256 tile, BK=64 ----------------
// Effective K = 3072 (3 bf16 segments). 512 threads = 8 waves (2M x 4N).
// Round-7 schedule (1 raw barrier per K-step, global_load_lds staging, linear
// LDS dest + XOR-pre-swizzled global source). NEW: 32x32x16 MFMA (faster pipe,
// half the MFMA instructions) + wave-parity K-slice stagger (odd waves run
// slices 2,3,0,1 so read bursts overlap the other parity's MFMA bursts).
// A/B frag: lane row = l&31, k = (l>>5)*8+e. C/D: col=lane&31,
// row=(reg&3)+8*(reg>>2)+4*(lane>>5)  [m74/m101-verified].
// MODE 1 (SYM):  C symmetric; 10 upper tiles; write splits at (i,j) and (j,i).
// MODE 2 (POLY): v = c2*C + c1*A + c0*I; symmetric writes like MODE 1.
// MODE 3 (XUP):  v = C; if(oh) splits + transposed splits; if(of) fp32.

#define SEGPTRS(S)                                                                        \
  const int seg_ = (S) >> 4, k0_ = ((S) & 15) << 6;                                       \
  const __hip_bfloat16* pa_ = seg_ == 0 ? pa0 : seg_ == 1 ? pa1 : pa2;                    \
  const __hip_bfloat16* pb_ = seg_ == 0 ? pb0 : seg_ == 1 ? pb1 : pb2;

// lane l of wave w stages row r = it*64 + w*8 + (l>>3), global chunk ((l&7)^(l>>3)),
// into linear LDS slot (row base + l*16). Image: LDS[r][slot] = chunk slot^(r&7).
#define STAGE_GL(DB, S)                                                                   \
  {                                                                                       \
    SEGPTRS(S)                                                                            \
    char* lb_ = smem + (DB) * 65536;                                                      \
    _Pragma("unroll") for (int it_ = 0; it_ < 4; ++it_) {                                 \
      const int r_ = it_ * 64 + w * 8 + (l >> 3);                                         \
      const int kx_ = k0_ + (((l & 7) ^ (l >> 3)) << 3);                                  \
      gload16(pa_ + boff + (size_t)(rowA + r_) * LDW + kx_,                               \
              lb_ + (it_ * 64 + w * 8) * 128 + l * 16);                                   \
      gload16(pb_ + boff + (size_t)(rowB + r_) * LDW + kx_,                               \
              lb_ + 32768 + (it_ * 64 + w * 8) * 128 + l * 16);                           \
    }                                                                                     \
  }

// one K-slice (K=16) of the step: 4 av + 2 bv reads, 8 x mfma_32x32x16
#define MFMA_SLICE(KS, BASE)                                                              \
  {                                                                                       \
    bf16x8 av[4], bv[2];                                                                  \
    _Pragma("unroll") for (int i_ = 0; i_ < 4; ++i_)                                      \
        av[i_] = *reinterpret_cast<const bf16x8*>(smem + (BASE) + offA[KS][i_]);          \
    _Pragma("unroll") for (int i_ = 0; i_ < 2; ++i_)                                      \
        bv[i_] = *reinterpret_cast<const bf16x8*>(smem + (BASE) + offB[KS][i_]);          \
    __builtin_amdgcn_s_setprio(1);                                                        \
    _Pragma("unroll") for (int mi_ = 0; mi_ < 4; ++mi_)                                   \
        _Pragma("unroll") for (int ni_ = 0; ni_ < 2; ++ni_)                               \
            acc[mi_][ni_] = __builtin_amdgcn_mfma_f32_32x32x16_bf16(                      \
                av[mi_], bv[ni_], acc[mi_][ni_], 0, 0, 0);                                \
    __builtin_amdgcn_s_setprio(0);                                                        \
  }

template <int MODE>
__global__ __launch_bounds__(512, 2) void k_gemm(
    const __hip_bfloat16* __restrict__ pa0, const __hip_bfloat16* __restrict__ pa1,
    const __hip_bfloat16* __restrict__ pa2, const __hip_bfloat16* __restrict__ pb0,
    const __hip_bfloat16* __restrict__ pb1, const __hip_bfloat16* __restrict__ pb2,
    __hip_bfloat16* oh, __hip_bfloat16* ol,
    __hip_bfloat16* oth, __hip_bfloat16* otl,
    float* __restrict__ of,
    const __hip_bfloat16* __restrict__ eh, const __hip_bfloat16* __restrict__ el,
    const float* __restrict__ coef) {
  __shared__ __align__(16) char smem[131072];  // 2 bufs x (A 32KB + B 32KB)
  const int t = threadIdx.x;
  const int w = t >> 6, l = t & 63;
  const int wr = w >> 2, wc = w & 3;  // 2M x 4N wave grid

  // Fully-bijective XCD-aware swizzle (m204): works for any gridDim.x.
  const int nwg = gridDim.x, q = nwg >> 3, r8 = nwg & 7;
  const int xcd = blockIdx.x & 7, o = blockIdx.x >> 3;
  const int wgid = (xcd < r8 ? xcd * (q + 1) : r8 * (q + 1) + (xcd - r8) * q) + o;

  int bat, tm, tn;
  if constexpr (MODE == 3) {
    bat = wgid >> 4;
    const int tile = wgid & 15;
    tm = tile >> 2; tn = tile & 3;
  } else {
    bat = (int)((unsigned)wgid / 10u);
    const int tile = wgid - bat * 10;
    tm = (tile < 4) ? 0 : (tile < 7) ? 1 : (tile < 9) ? 2 : 3;
    tn = (tile < 4) ? tile : (tile < 7) ? (tile - 3) : (tile < 9) ? (tile - 5) : 3;
  }
  const size_t boff = (size_t)bat << BATCH_SH;
  const int rowA = tm * 256, rowB = tn * 256;

  f32x16 acc[4][2];
#pragma unroll
  for (int i = 0; i < 4; ++i)
#pragma unroll
    for (int j = 0; j < 2; ++j) acc[i][j] = (f32x16)(0.f);

  // MFMA fragment LDS byte offsets (within a buffer), XOR chunk swizzle.
  // K-slice ks (K=16): chunk c = ks*2 + (l>>5); row = l&31 within 32-row frag.
  int offA[4][4], offB[4][2];
#pragma unroll
  for (int ks = 0; ks < 4; ++ks) {
    const int c = ks * 2 + (l >> 5);
#pragma unroll
    for (int mi = 0; mi < 4; ++mi) {
      const int rA = wr * 128 + mi * 32 + (l & 31);
      offA[ks][mi] = rA * 128 + ((c ^ (rA & 7)) << 4);
    }
#pragma unroll
    for (int ni = 0; ni < 2; ++ni) {
      const int rB = wc * 64 + ni * 32 + (l & 31);
      offB[ks][ni] = 32768 + rB * 128 + ((c ^ (rB & 7)) << 4);
    }
  }

  // prologue: stage tile 0 into buf0, drain, converge
  STAGE_GL(0, 0);
  asm volatile("s_waitcnt vmcnt(0)" ::: "memory");
  __builtin_amdgcn_sched_barrier(0);
  __builtin_amdgcn_s_barrier();
  __builtin_amdgcn_sched_barrier(0);

  for (int s = 0; s < 48; ++s) {
    const int base = (s & 1) * 65536;
    if (s + 1 < 48) STAGE_GL((s & 1) ^ 1, s + 1);  // issue early; in flight under MFMA
    __builtin_amdgcn_sched_barrier(0);             // pin issue before compute
    if ((w & 1) == 0) {                            // parity-staggered K-slice order
      MFMA_SLICE(0, base); MFMA_SLICE(1, base); MFMA_SLICE(2, base); MFMA_SLICE(3, base);
    } else {
      MFMA_SLICE(2, base); MFMA_SLICE(3, base); MFMA_SLICE(0, base); MFMA_SLICE(1, base);
    }
    // tile s+1 loads retired (issued ~full step ago -> cheap) + my reads done (WAR)
    asm volatile("s_waitcnt vmcnt(0) lgkmcnt(0)" ::: "memory");
    __builtin_amdgcn_sched_barrier(0);
    __builtin_amdgcn_s_barrier();
    __builtin_amdgcn_sched_barrier(0);
  }

  float c0 = 0.f, c1 = 0.f, c2 = 0.f;
  if constexpr (MODE == 2) { c0 = coef[0]; c1 = coef[1]; c2 = coef[2]; }
  // C/D 32x32 layout: col = lane&31, row = (reg&3) + 8*(reg>>2) + 4*(lane>>5)
  const int lane31 = l & 31, hi5 = l >> 5;
  const int r00 = tm * 256 + wr * 128 + 4 * hi5;
  const int cb = tn * 256 + wc * 64 + lane31;
#pragma unroll
  for (int mi = 0; mi < 4; ++mi) {
#pragma unroll
    for (int ni = 0; ni < 2; ++ni) {
      const int ccol = cb + ni * 32;
#pragma unroll
      for (int reg = 0; reg < 16; ++reg) {
        const int rrow = r00 + mi * 32 + (reg & 3) + 8 * (reg >> 2);
        const size_t idx = boff + (size_t)rrow * LDW + ccol;
        const size_t tix = boff + (size_t)ccol * LDW + rrow;
        float v = acc[mi][ni][reg];
        if constexpr (MODE == 2)
          v = c2 * v + c1 * (b2f(eh[idx]) + b2f(el[idx])) + (rrow == ccol ? c0 : 0.f);
        __hip_bfloat16 h = f2b(v);
        __hip_bfloat16 lo = f2b(v - b2f(h));
        if constexpr (MODE == 3) {
          if (oh) {
            oh[idx] = h; ol[idx] = lo;
            oth[tix] = h; otl[tix] = lo;
          }
          if (of) of[idx] = v;
        } else {
          oh[idx] = h; ol[idx] = lo;
          if (tm != tn) { oth[tix] = h; otl[tix] = lo; }
        }
      }
    }
  }
}

extern "C" void kernel_launch(void* const* d_in, const int* in_sizes, int n_in,
                              void* d_out, int out_size, void* d_ws, size_t ws_size,
                              hipStream_t stream) {
  (void)in_sizes; (void)n_in; (void)out_size;
  const float* xin = (const float*)d_in[0];
  const float* coef = (const float*)d_in[1];
  float* xout = (float*)d_out;

  // ws need: 8 bf16 buffers (4 pairs) x CH x 2MB = 16 MB/batch (+64KB slack)
  int CH = 64;
  while (CH > 1 && ((size_t)CH * 16u * 1024u * 1024u + 65536u) > ws_size) CH >>= 1;

  const size_t nE = (size_t)CH << BATCH_SH;
  __hip_bfloat16* P0h = (__hip_bfloat16*)d_ws;
  __hip_bfloat16* P0l = P0h + nE;
  __hip_bfloat16* P1h = P0l + nE;
  __hip_bfloat16* P1l = P1h + nE;
  __hip_bfloat16* P2h = P1l + nE;
  __hip_bfloat16* P2l = P2h + nE;
  __hip_bfloat16* XTh = P2l + nE;
  __hip_bfloat16* XTl = XTh + nE;
  float* partials = (float*)(XTl + nE);
  float* scales = partials + (size_t)CH * 64;

  for (int c = 0; c < 64; c += CH) {
    const float* xi = xin + ((size_t)c << BATCH_SH);
    float* X = xout + ((size_t)c << BATCH_SH);  // final fp32 output only
    k_partial<<<dim3(64, CH), 256, 0, stream>>>(xi, partials);
    k_scale<<<dim3(CH), 64, 0, stream>>>(partials, scales);
    k_scalesplit<<<dim3(16, 16, CH), 256, 0, stream>>>(xi, scales, P0h, P0l, XTh, XTl);

    // rotating pairs: X, A, B  (X_next reuses the dead A pair each iteration)
    __hip_bfloat16 *Xh = P0h, *Xl = P0l, *Ah = P1h, *Al = P1l, *Bh = P2h, *Bl = P2l;
    for (int it = 0; it < 5; ++it) {
      // A = XT * XT^T (symmetric, 10 upper tiles): hi*hi + hi*lo + lo*hi
      k_gemm<1><<<dim3(CH * 10), 512, 0, stream>>>(XTh, XTh, XTl, XTh, XTl, XTh,
                                                   Ah, Al, Ah, Al, nullptr,
                                                   nullptr, nullptr, nullptr);
      // B = c2*A^2 + c1*A + c0*I (symmetric, 10 upper tiles)
      k_gemm<2><<<dim3(CH * 10), 512, 0, stream>>>(Ah, Ah, Al, Ah, Al, Ah,
                                                   Bh, Bl, Bh, Bl, nullptr,
                                                   Ah, Al, coef);
      // X_next = X * B^T (B symmetric); splits -> dead A pair; XT splits in place
      k_gemm<3><<<dim3(CH * 16), 512, 0, stream>>>(Xh, Xh, Xl, Bh, Bl, Bh,
                                                   (it < 4) ? Ah : nullptr,
                                                   (it < 4) ? Al : nullptr,
                                                   XTh, XTl,
                                                   (it == 4) ? X : nullptr,
                                                   nullptr, nullptr, nullptr);
      // rotate (X, A, B) <- (A, B, X)
      __hip_bfloat16 *th = Xh, *tl = Xl;
      Xh = Ah; Xl = Al;
      Ah = Bh; Al = Bl;
      Bh = th; Bl = tl;
    }
  }
}

// Round 10
// 8120.106 us; speedup vs baseline: 1.3380x; 1.3380x over previous
//
#include <hip/hip_runtime.h>
#include <hip/hip_bf16.h>
#include <stdint.h>

typedef float f32x4 __attribute__((ext_vector_type(4)));
typedef short bf16x8 __attribute__((ext_vector_type(8)));

#define LDW 1024
#define BATCH_SH 20  // 1<<20 elements per 1024x1024 matrix

__device__ __forceinline__ float b2f(__hip_bfloat16 h) { return __bfloat162float(h); }
__device__ __forceinline__ __hip_bfloat16 f2b(float f) { return __float2bfloat16(f); }

__device__ __forceinline__ void gload16(const void* g, void* l) {
  __builtin_amdgcn_global_load_lds((const __attribute__((address_space(1))) void*)g,
                                   (__attribute__((address_space(3))) void*)l,
                                   16, 0, 0);
}

// ---------------- Frobenius norm (2-stage) ----------------
__global__ void k_partial(const float* __restrict__ xin, float* __restrict__ partials) {
  const int b = blockIdx.y, ch = blockIdx.x, t = threadIdx.x;
  const size_t base = ((size_t)b << BATCH_SH) + (size_t)ch * 16384;
  float s = 0.f;
#pragma unroll
  for (int i = 0; i < 16; ++i) {
    f32x4 v = *reinterpret_cast<const f32x4*>(xin + base + (size_t)(i * 256 + t) * 4);
    s += v[0] * v[0] + v[1] * v[1] + v[2] * v[2] + v[3] * v[3];
  }
#pragma unroll
  for (int off = 32; off; off >>= 1) s += __shfl_down(s, off);
  __shared__ float red[4];
  if ((t & 63) == 0) red[t >> 6] = s;
  __syncthreads();
  if (t == 0) partials[b * 64 + ch] = red[0] + red[1] + red[2] + red[3];
}

__global__ void k_scale(const float* __restrict__ partials, float* __restrict__ scales) {
  const int b = blockIdx.x, t = threadIdx.x;
  float s = partials[b * 64 + t];
#pragma unroll
  for (int off = 32; off; off >>= 1) s += __shfl_down(s, off);
  if (t == 0) scales[b] = 1.1f / sqrtf(s);
}

// ---------------- scale + split + transpose-split ----------------
__global__ void k_scalesplit(const float* __restrict__ xin, const float* __restrict__ scales,
                             __hip_bfloat16* __restrict__ Xh, __hip_bfloat16* __restrict__ Xl,
                             __hip_bfloat16* __restrict__ XTh, __hip_bfloat16* __restrict__ XTl) {
  __shared__ float tile[64][65];
  const int b = blockIdx.z, tm = blockIdx.y, tn = blockIdx.x;
  const size_t boff = (size_t)b << BATCH_SH;
  const float s = scales[b];
  const int t = threadIdx.x, lr0 = t >> 6, lc = t & 63;
#pragma unroll
  for (int p = 0; p < 16; ++p) {
    const int lr = p * 4 + lr0;
    const size_t idx = boff + (size_t)(tm * 64 + lr) * LDW + tn * 64 + lc;
    const float v = xin[idx] * s;
    __hip_bfloat16 h = f2b(v);
    Xh[idx] = h;
    Xl[idx] = f2b(v - b2f(h));
    tile[lr][lc] = v;
  }
  __syncthreads();
#pragma unroll
  for (int p = 0; p < 16; ++p) {
    const int lr = p * 4 + lr0;
    const float v = tile[lc][lr];
    const size_t idx = boff + (size_t)(tn * 64 + lr) * LDW + tm * 64 + lc;
    __hip_bfloat16 h = f2b(v);
    XTh[idx] = h;
    XTl[idx] = f2b(v - b2f(h));
  }
}

// ---------------- split-bf16 GEMM: C = PA * PB^T, 128x256 tile, BK=64 ----------------
// Effective K = 3072 (3 bf16 segments). 512 threads = 8 waves (2M x 4N),
// per-wave output 64x64. Round-7 schedule verbatim: 1 raw s_barrier per K-step,
// global_load_lds staging (linear LDS dest + XOR-pre-swizzled global source),
// vmcnt(0)+lgkmcnt(0) drained once per step. LDS 2 x 48KB.
// Half-tile geometry makes sym grids 1280 = 5.0 exact CU-rounds (no tail) and
// xup 2048 = 8.0 exact rounds.
// MODE 1 (SYM):  full 256-tile (i,j) i<=j covered by half-tiles (2i+h, j);
//                mirror-write when i != j.
// MODE 2 (POLY): v = c2*C + c1*A + c0*I; mirror like MODE 1.
// MODE 3 (XUP):  v = C; if(oh) splits + transposed splits; if(of) fp32.

#define SEGPTRS(S)                                                                        \
  const int seg_ = (S) >> 4, k0_ = ((S) & 15) << 6;                                       \
  const __hip_bfloat16* pa_ = seg_ == 0 ? pa0 : seg_ == 1 ? pa1 : pa2;                    \
  const __hip_bfloat16* pb_ = seg_ == 0 ? pb0 : seg_ == 1 ? pb1 : pb2;

// lane l of wave w stages row r = it*64 + w*8 + (l>>3), global chunk ((l&7)^(l>>3)),
// into linear LDS slot (row base + l*16). Image: LDS[r][slot] = chunk slot^(r&7).
#define STAGE_GL(DB, S)                                                                   \
  {                                                                                       \
    SEGPTRS(S)                                                                            \
    char* lb_ = smem + (DB) * 49152;                                                      \
    _Pragma("unroll") for (int it_ = 0; it_ < 2; ++it_) {                                 \
      const int r_ = it_ * 64 + w * 8 + (l >> 3);                                         \
      const int kx_ = k0_ + (((l & 7) ^ (l >> 3)) << 3);                                  \
      gload16(pa_ + boff + (size_t)(rowA + r_) * LDW + kx_,                               \
              lb_ + (it_ * 64 + w * 8) * 128 + l * 16);                                   \
    }                                                                                     \
    _Pragma("unroll") for (int it_ = 0; it_ < 4; ++it_) {                                 \
      const int r_ = it_ * 64 + w * 8 + (l >> 3);                                         \
      const int kx_ = k0_ + (((l & 7) ^ (l >> 3)) << 3);                                  \
      gload16(pb_ + boff + (size_t)(rowB + r_) * LDW + kx_,                               \
              lb_ + 16384 + (it_ * 64 + w * 8) * 128 + l * 16);                           \
    }                                                                                     \
  }

#define MFMA_PHASE(KK, BASE)                                                              \
  {                                                                                       \
    bf16x8 av[4], bv[4];                                                                  \
    _Pragma("unroll") for (int mi_ = 0; mi_ < 4; ++mi_)                                   \
        av[mi_] = *reinterpret_cast<const bf16x8*>(smem + (BASE) + offA[KK][mi_]);        \
    _Pragma("unroll") for (int ni_ = 0; ni_ < 4; ++ni_)                                   \
        bv[ni_] = *reinterpret_cast<const bf16x8*>(smem + (BASE) + offB[KK][ni_]);        \
    __builtin_amdgcn_s_setprio(1);                                                        \
    _Pragma("unroll") for (int mi_ = 0; mi_ < 4; ++mi_)                                   \
        _Pragma("unroll") for (int ni_ = 0; ni_ < 4; ++ni_)                               \
            acc[mi_][ni_] = __builtin_amdgcn_mfma_f32_16x16x32_bf16(                      \
                av[mi_], bv[ni_], acc[mi_][ni_], 0, 0, 0);                                \
    __builtin_amdgcn_s_setprio(0);                                                        \
  }

template <int MODE>
__global__ __launch_bounds__(512, 2) void k_gemm(
    const __hip_bfloat16* __restrict__ pa0, const __hip_bfloat16* __restrict__ pa1,
    const __hip_bfloat16* __restrict__ pa2, const __hip_bfloat16* __restrict__ pb0,
    const __hip_bfloat16* __restrict__ pb1, const __hip_bfloat16* __restrict__ pb2,
    __hip_bfloat16* oh, __hip_bfloat16* ol,
    __hip_bfloat16* oth, __hip_bfloat16* otl,
    float* __restrict__ of,
    const __hip_bfloat16* __restrict__ eh, const __hip_bfloat16* __restrict__ el,
    const float* __restrict__ coef) {
  __shared__ __align__(16) char smem[98304];  // 2 bufs x (A 16KB + B 32KB)
  const int t = threadIdx.x;
  const int w = t >> 6, l = t & 63;
  const int wr = w >> 2, wc = w & 3;  // 2M x 4N wave grid; wave out 64x64

  // Fully-bijective XCD-aware swizzle (m204): works for any gridDim.x.
  const int nwg = gridDim.x, q = nwg >> 3, r8 = nwg & 7;
  const int xcd = blockIdx.x & 7, o = blockIdx.x >> 3;
  const int wgid = (xcd < r8 ? xcd * (q + 1) : r8 * (q + 1) + (xcd - r8) * q) + o;

  int bat, tm, tn;
  bool mir = false;
  if constexpr (MODE == 3) {
    bat = wgid >> 5;
    const int tile = wgid & 31;
    tm = tile >> 2; tn = tile & 3;  // tm in 128-units (0..7), tn in 256-units (0..3)
  } else {
    bat = (int)((unsigned)wgid / 20u);
    const int ht = wgid - bat * 20;
    const int p = ht >> 1, half = ht & 1;
    const int i = (p < 4) ? 0 : (p < 7) ? 1 : (p < 9) ? 2 : 3;
    const int j = (p < 4) ? p : (p < 7) ? (p - 3) : (p < 9) ? (p - 5) : 3;
    tm = 2 * i + half;  // 128-unit row block
    tn = j;             // 256-unit col block
    mir = (i != j);
  }
  const size_t boff = (size_t)bat << BATCH_SH;
  const int rowA = tm * 128, rowB = tn * 256;

  f32x4 acc[4][4];
#pragma unroll
  for (int i = 0; i < 4; ++i)
#pragma unroll
    for (int j = 0; j < 4; ++j) acc[i][j] = (f32x4){0.f, 0.f, 0.f, 0.f};

  // MFMA fragment LDS byte offsets (within a buffer), XOR chunk swizzle
  int offA[2][4], offB[2][4];
#pragma unroll
  for (int kk = 0; kk < 2; ++kk) {
    const int g = kk * 4 + (l >> 4);
#pragma unroll
    for (int mi = 0; mi < 4; ++mi) {
      const int rA = wr * 64 + mi * 16 + (l & 15);
      offA[kk][mi] = rA * 128 + ((g ^ (rA & 7)) << 4);
    }
#pragma unroll
    for (int ni = 0; ni < 4; ++ni) {
      const int rB = wc * 64 + ni * 16 + (l & 15);
      offB[kk][ni] = 16384 + rB * 128 + ((g ^ (rB & 7)) << 4);
    }
  }

  // prologue: stage tile 0 into buf0, drain, converge
  STAGE_GL(0, 0);
  asm volatile("s_waitcnt vmcnt(0)" ::: "memory");
  __builtin_amdgcn_sched_barrier(0);
  __builtin_amdgcn_s_barrier();
  __builtin_amdgcn_sched_barrier(0);

  for (int s = 0; s < 48; ++s) {
    const int base = (s & 1) * 49152;
    if (s + 1 < 48) STAGE_GL((s & 1) ^ 1, s + 1);  // issue early; in flight under MFMA
    __builtin_amdgcn_sched_barrier(0);             // pin issue before compute
    MFMA_PHASE(0, base);
    MFMA_PHASE(1, base);
    // tile s+1 loads retired (issued ~full step ago -> cheap) + my reads done (WAR)
    asm volatile("s_waitcnt vmcnt(0) lgkmcnt(0)" ::: "memory");
    __builtin_amdgcn_sched_barrier(0);
    __builtin_amdgcn_s_barrier();
    __builtin_amdgcn_sched_barrier(0);
  }

  float c0 = 0.f, c1 = 0.f, c2 = 0.f;
  if constexpr (MODE == 2) { c0 = coef[0]; c1 = coef[1]; c2 = coef[2]; }
  const int r0 = tm * 128 + wr * 64 + ((l >> 4) << 2);
  const int cb = tn * 256 + wc * 64 + (l & 15);
#pragma unroll
  for (int mi = 0; mi < 4; ++mi) {
#pragma unroll
    for (int ni = 0; ni < 4; ++ni) {
      const int ccol = cb + ni * 16;
#pragma unroll
      for (int j = 0; j < 4; ++j) {
        const int rrow = r0 + mi * 16 + j;
        const size_t idx = boff + (size_t)rrow * LDW + ccol;
        const size_t tix = boff + (size_t)ccol * LDW + rrow;
        float v = acc[mi][ni][j];
        if constexpr (MODE == 2)
          v = c2 * v + c1 * (b2f(eh[idx]) + b2f(el[idx])) + (rrow == ccol ? c0 : 0.f);
        __hip_bfloat16 h = f2b(v);
        __hip_bfloat16 lo = f2b(v - b2f(h));
        if constexpr (MODE == 3) {
          if (oh) {
            oh[idx] = h; ol[idx] = lo;
            oth[tix] = h; otl[tix] = lo;
          }
          if (of) of[idx] = v;
        } else {
          oh[idx] = h; ol[idx] = lo;
          if (mir) { oth[tix] = h; otl[tix] = lo; }
        }
      }
    }
  }
}

extern "C" void kernel_launch(void* const* d_in, const int* in_sizes, int n_in,
                              void* d_out, int out_size, void* d_ws, size_t ws_size,
                              hipStream_t stream) {
  (void)in_sizes; (void)n_in; (void)out_size;
  const float* xin = (const float*)d_in[0];
  const float* coef = (const float*)d_in[1];
  float* xout = (float*)d_out;

  // ws need: 8 bf16 buffers (4 pairs) x CH x 2MB = 16 MB/batch (+64KB slack)
  int CH = 64;
  while (CH > 1 && ((size_t)CH * 16u * 1024u * 1024u + 65536u) > ws_size) CH >>= 1;

  const size_t nE = (size_t)CH << BATCH_SH;
  __hip_bfloat16* P0h = (__hip_bfloat16*)d_ws;
  __hip_bfloat16* P0l = P0h + nE;
  __hip_bfloat16* P1h = P0l + nE;
  __hip_bfloat16* P1l = P1h + nE;
  __hip_bfloat16* P2h = P1l + nE;
  __hip_bfloat16* P2l = P2h + nE;
  __hip_bfloat16* XTh = P2l + nE;
  __hip_bfloat16* XTl = XTh + nE;
  float* partials = (float*)(XTl + nE);
  float* scales = partials + (size_t)CH * 64;

  for (int c = 0; c < 64; c += CH) {
    const float* xi = xin + ((size_t)c << BATCH_SH);
    float* X = xout + ((size_t)c << BATCH_SH);  // final fp32 output only
    k_partial<<<dim3(64, CH), 256, 0, stream>>>(xi, partials);
    k_scale<<<dim3(CH), 64, 0, stream>>>(partials, scales);
    k_scalesplit<<<dim3(16, 16, CH), 256, 0, stream>>>(xi, scales, P0h, P0l, XTh, XTl);

    // rotating pairs: X, A, B  (X_next reuses the dead A pair each iteration)
    __hip_bfloat16 *Xh = P0h, *Xl = P0l, *Ah = P1h, *Al = P1l, *Bh = P2h, *Bl = P2l;
    for (int it = 0; it < 5; ++it) {
      // A = XT * XT^T (symmetric, 20 upper half-tiles): hi*hi + hi*lo + lo*hi
      k_gemm<1><<<dim3(CH * 20), 512, 0, stream>>>(XTh, XTh, XTl, XTh, XTl, XTh,
                                                   Ah, Al, Ah, Al, nullptr,
                                                   nullptr, nullptr, nullptr);
      // B = c2*A^2 + c1*A + c0*I (symmetric, 20 upper half-tiles)
      k_gemm<2><<<dim3(CH * 20), 512, 0, stream>>>(Ah, Ah, Al, Ah, Al, Ah,
                                                   Bh, Bl, Bh, Bl, nullptr,
                                                   Ah, Al, coef);
      // X_next = X * B^T (B symmetric); splits -> dead A pair; XT splits in place
      k_gemm<3><<<dim3(CH * 32), 512, 0, stream>>>(Xh, Xh, Xl, Bh, Bl, Bh,
                                                   (it < 4) ? Ah : nullptr,
                                                   (it < 4) ? Al : nullptr,
                                                   XTh, XTl,
                                                   (it == 4) ? X : nullptr,
                                                   nullptr, nullptr, nullptr);
      // rotate (X, A, B) <- (A, B, X)
      __hip_bfloat16 *th = Xh, *tl = Xl;
      Xh = Ah; Xl = Al;
      Ah = Bh; Al = Bl;
      Bh = th; Bl = tl;
    }
  }
}

// Round 11
// 7487.263 us; speedup vs baseline: 1.4510x; 1.0845x over previous
//
#include <hip/hip_runtime.h>
#include <hip/hip_bf16.h>
#include <stdint.h>

typedef float f32x4 __attribute__((ext_vector_type(4)));
typedef short bf16x8 __attribute__((ext_vector_type(8)));

#define LDW 1024
#define BATCH_SH 20  // 1<<20 elements per 1024x1024 matrix

__device__ __forceinline__ float b2f(__hip_bfloat16 h) { return __bfloat162float(h); }
__device__ __forceinline__ __hip_bfloat16 f2b(float f) { return __float2bfloat16(f); }

__device__ __forceinline__ void gload16(const void* g, void* l) {
  __builtin_amdgcn_global_load_lds((const __attribute__((address_space(1))) void*)g,
                                   (__attribute__((address_space(3))) void*)l,
                                   16, 0, 0);
}

// ---------------- Frobenius norm (2-stage) ----------------
__global__ void k_partial(const float* __restrict__ xin, float* __restrict__ partials) {
  const int b = blockIdx.y, ch = blockIdx.x, t = threadIdx.x;
  const size_t base = ((size_t)b << BATCH_SH) + (size_t)ch * 16384;
  float s = 0.f;
#pragma unroll
  for (int i = 0; i < 16; ++i) {
    f32x4 v = *reinterpret_cast<const f32x4*>(xin + base + (size_t)(i * 256 + t) * 4);
    s += v[0] * v[0] + v[1] * v[1] + v[2] * v[2] + v[3] * v[3];
  }
#pragma unroll
  for (int off = 32; off; off >>= 1) s += __shfl_down(s, off);
  __shared__ float red[4];
  if ((t & 63) == 0) red[t >> 6] = s;
  __syncthreads();
  if (t == 0) partials[b * 64 + ch] = red[0] + red[1] + red[2] + red[3];
}

__global__ void k_scale(const float* __restrict__ partials, float* __restrict__ scales) {
  const int b = blockIdx.x, t = threadIdx.x;
  float s = partials[b * 64 + t];
#pragma unroll
  for (int off = 32; off; off >>= 1) s += __shfl_down(s, off);
  if (t == 0) scales[b] = 1.1f / sqrtf(s);
}

// ---------------- scale + split + transpose-split ----------------
__global__ void k_scalesplit(const float* __restrict__ xin, const float* __restrict__ scales,
                             __hip_bfloat16* __restrict__ Xh, __hip_bfloat16* __restrict__ Xl,
                             __hip_bfloat16* __restrict__ XTh, __hip_bfloat16* __restrict__ XTl) {
  __shared__ float tile[64][65];
  const int b = blockIdx.z, tm = blockIdx.y, tn = blockIdx.x;
  const size_t boff = (size_t)b << BATCH_SH;
  const float s = scales[b];
  const int t = threadIdx.x, lr0 = t >> 6, lc = t & 63;
#pragma unroll
  for (int p = 0; p < 16; ++p) {
    const int lr = p * 4 + lr0;
    const size_t idx = boff + (size_t)(tm * 64 + lr) * LDW + tn * 64 + lc;
    const float v = xin[idx] * s;
    __hip_bfloat16 h = f2b(v);
    Xh[idx] = h;
    Xl[idx] = f2b(v - b2f(h));
    tile[lr][lc] = v;
  }
  __syncthreads();
#pragma unroll
  for (int p = 0; p < 16; ++p) {
    const int lr = p * 4 + lr0;
    const float v = tile[lc][lr];
    const size_t idx = boff + (size_t)(tn * 64 + lr) * LDW + tm * 64 + lc;
    __hip_bfloat16 h = f2b(v);
    XTh[idx] = h;
    XTl[idx] = f2b(v - b2f(h));
  }
}

// ---------------- bf16-pair transpose: (Xh,Xl) -> (XTh,XTl), all coalesced ----------------
__global__ void k_transpose(const unsigned short* __restrict__ Xh,
                            const unsigned short* __restrict__ Xl,
                            unsigned short* __restrict__ XTh,
                            unsigned short* __restrict__ XTl) {
  __shared__ unsigned tile[64][65];  // packed (h | l<<16); stride 65 words: conflict-free cols
  const int b = blockIdx.z, tm = blockIdx.y, tn = blockIdx.x;
  const size_t boff = (size_t)b << BATCH_SH;
  const int t = threadIdx.x, lr0 = t >> 6, lc = t & 63;
#pragma unroll
  for (int p = 0; p < 16; ++p) {
    const int lr = p * 4 + lr0;
    const size_t idx = boff + (size_t)(tm * 64 + lr) * LDW + tn * 64 + lc;
    const unsigned h = Xh[idx], l = Xl[idx];
    tile[lr][lc] = h | (l << 16);
  }
  __syncthreads();
#pragma unroll
  for (int p = 0; p < 16; ++p) {
    const int lr = p * 4 + lr0;
    const unsigned v = tile[lc][lr];
    const size_t idx = boff + (size_t)(tn * 64 + lr) * LDW + tm * 64 + lc;
    XTh[idx] = (unsigned short)(v & 0xffffu);
    XTl[idx] = (unsigned short)(v >> 16);
  }
}

// ---------------- split-bf16 GEMM: C = PA * PB^T, 256x256 tile, BK=64 ----------------
// Effective K = 3072 (3 bf16 segments). 512 threads = 8 waves (2M x 4N).
// Round-7 schedule: 1 raw s_barrier per K-step, global_load_lds staging (linear
// LDS dest + XOR-pre-swizzled global source), vmcnt(0)+lgkmcnt(0) drained once
// per step.
// MODE 1 (SYM):  C symmetric; 10 upper tiles; write splits at (i,j) and (j,i).
// MODE 2 (POLY): v = c2*C + c1*A + c0*I; symmetric writes like MODE 1.
// MODE 3 (XUP):  v = C; if(oh) coalesced splits only (transpose done by
//                k_transpose); if(of) fp32.

#define SEGPTRS(S)                                                                        \
  const int seg_ = (S) >> 4, k0_ = ((S) & 15) << 6;                                       \
  const __hip_bfloat16* pa_ = seg_ == 0 ? pa0 : seg_ == 1 ? pa1 : pa2;                    \
  const __hip_bfloat16* pb_ = seg_ == 0 ? pb0 : seg_ == 1 ? pb1 : pb2;

// lane l of wave w stages row r = it*64 + w*8 + (l>>3), global chunk ((l&7)^(l>>3)),
// into linear LDS slot (row base + l*16). Image: LDS[r][slot] = chunk slot^(r&7).
#define STAGE_GL(DB, S)                                                                   \
  {                                                                                       \
    SEGPTRS(S)                                                                            \
    char* lb_ = smem + (DB) * 65536;                                                      \
    _Pragma("unroll") for (int it_ = 0; it_ < 4; ++it_) {                                 \
      const int r_ = it_ * 64 + w * 8 + (l >> 3);                                         \
      const int kx_ = k0_ + (((l & 7) ^ (l >> 3)) << 3);                                  \
      gload16(pa_ + boff + (size_t)(rowA + r_) * LDW + kx_,                               \
              lb_ + (it_ * 64 + w * 8) * 128 + l * 16);                                   \
      gload16(pb_ + boff + (size_t)(rowB + r_) * LDW + kx_,                               \
              lb_ + 32768 + (it_ * 64 + w * 8) * 128 + l * 16);                           \
    }                                                                                     \
  }

#define MFMA_PHASE(KK, BASE)                                                              \
  {                                                                                       \
    bf16x8 av[8], bv[4];                                                                  \
    _Pragma("unroll") for (int mi_ = 0; mi_ < 8; ++mi_)                                   \
        av[mi_] = *reinterpret_cast<const bf16x8*>(smem + (BASE) + offA[KK][mi_]);        \
    _Pragma("unroll") for (int ni_ = 0; ni_ < 4; ++ni_)                                   \
        bv[ni_] = *reinterpret_cast<const bf16x8*>(smem + (BASE) + offB[KK][ni_]);        \
    __builtin_amdgcn_s_setprio(1);                                                        \
    _Pragma("unroll") for (int mi_ = 0; mi_ < 8; ++mi_)                                   \
        _Pragma("unroll") for (int ni_ = 0; ni_ < 4; ++ni_)                               \
            acc[mi_][ni_] = __builtin_amdgcn_mfma_f32_16x16x32_bf16(                      \
                av[mi_], bv[ni_], acc[mi_][ni_], 0, 0, 0);                                \
    __builtin_amdgcn_s_setprio(0);                                                        \
  }

template <int MODE>
__global__ __launch_bounds__(512, 2) void k_gemm(
    const __hip_bfloat16* __restrict__ pa0, const __hip_bfloat16* __restrict__ pa1,
    const __hip_bfloat16* __restrict__ pa2, const __hip_bfloat16* __restrict__ pb0,
    const __hip_bfloat16* __restrict__ pb1, const __hip_bfloat16* __restrict__ pb2,
    __hip_bfloat16* oh, __hip_bfloat16* ol,
    __hip_bfloat16* oth, __hip_bfloat16* otl,
    float* __restrict__ of,
    const __hip_bfloat16* __restrict__ eh, const __hip_bfloat16* __restrict__ el,
    const float* __restrict__ coef) {
  __shared__ __align__(16) char smem[131072];  // 2 bufs x (A 32KB + B 32KB)
  const int t = threadIdx.x;
  const int w = t >> 6, l = t & 63;
  const int wr = w >> 2, wc = w & 3;  // 2M x 4N wave grid

  // Fully-bijective XCD-aware swizzle (m204): works for any gridDim.x.
  const int nwg = gridDim.x, q = nwg >> 3, r8 = nwg & 7;
  const int xcd = blockIdx.x & 7, o = blockIdx.x >> 3;
  const int wgid = (xcd < r8 ? xcd * (q + 1) : r8 * (q + 1) + (xcd - r8) * q) + o;

  int bat, tm, tn;
  if constexpr (MODE == 3) {
    bat = wgid >> 4;
    const int tile = wgid & 15;
    tm = tile >> 2; tn = tile & 3;
  } else {
    bat = (int)((unsigned)wgid / 10u);
    const int tile = wgid - bat * 10;
    tm = (tile < 4) ? 0 : (tile < 7) ? 1 : (tile < 9) ? 2 : 3;
    tn = (tile < 4) ? tile : (tile < 7) ? (tile - 3) : (tile < 9) ? (tile - 5) : 3;
  }
  const size_t boff = (size_t)bat << BATCH_SH;
  const int rowA = tm * 256, rowB = tn * 256;

  f32x4 acc[8][4];
#pragma unroll
  for (int i = 0; i < 8; ++i)
#pragma unroll
    for (int j = 0; j < 4; ++j) acc[i][j] = (f32x4){0.f, 0.f, 0.f, 0.f};

  // MFMA fragment LDS byte offsets (within a buffer), XOR chunk swizzle
  int offA[2][8], offB[2][4];
#pragma unroll
  for (int kk = 0; kk < 2; ++kk) {
    const int g = kk * 4 + (l >> 4);
#pragma unroll
    for (int mi = 0; mi < 8; ++mi) {
      const int rA = wr * 128 + mi * 16 + (l & 15);
      offA[kk][mi] = rA * 128 + ((g ^ (rA & 7)) << 4);
    }
#pragma unroll
    for (int ni = 0; ni < 4; ++ni) {
      const int rB = wc * 64 + ni * 16 + (l & 15);
      offB[kk][ni] = 32768 + rB * 128 + ((g ^ (rB & 7)) << 4);
    }
  }

  // prologue: stage tile 0 into buf0, drain, converge
  STAGE_GL(0, 0);
  asm volatile("s_waitcnt vmcnt(0)" ::: "memory");
  __builtin_amdgcn_sched_barrier(0);
  __builtin_amdgcn_s_barrier();
  __builtin_amdgcn_sched_barrier(0);

  for (int s = 0; s < 48; ++s) {
    const int base = (s & 1) * 65536;
    if (s + 1 < 48) STAGE_GL((s & 1) ^ 1, s + 1);  // issue early; in flight under MFMA
    __builtin_amdgcn_sched_barrier(0);             // pin issue before compute
    MFMA_PHASE(0, base);
    MFMA_PHASE(1, base);
    // tile s+1 loads retired (issued ~full step ago -> cheap) + my reads done (WAR)
    asm volatile("s_waitcnt vmcnt(0) lgkmcnt(0)" ::: "memory");
    __builtin_amdgcn_sched_barrier(0);
    __builtin_amdgcn_s_barrier();
    __builtin_amdgcn_sched_barrier(0);
  }

  float c0 = 0.f, c1 = 0.f, c2 = 0.f;
  if constexpr (MODE == 2) { c0 = coef[0]; c1 = coef[1]; c2 = coef[2]; }
  const int r0 = tm * 256 + wr * 128 + ((l >> 4) << 2);
  const int cb = tn * 256 + wc * 64 + (l & 15);
#pragma unroll
  for (int mi = 0; mi < 8; ++mi) {
#pragma unroll
    for (int ni = 0; ni < 4; ++ni) {
      const int ccol = cb + ni * 16;
#pragma unroll
      for (int j = 0; j < 4; ++j) {
        const int rrow = r0 + mi * 16 + j;
        const size_t idx = boff + (size_t)rrow * LDW + ccol;
        float v = acc[mi][ni][j];
        if constexpr (MODE == 2)
          v = c2 * v + c1 * (b2f(eh[idx]) + b2f(el[idx])) + (rrow == ccol ? c0 : 0.f);
        __hip_bfloat16 h = f2b(v);
        __hip_bfloat16 lo = f2b(v - b2f(h));
        if constexpr (MODE == 3) {
          if (oh) { oh[idx] = h; ol[idx] = lo; }
          if (of) of[idx] = v;
        } else {
          oh[idx] = h; ol[idx] = lo;
          if (tm != tn) {
            const size_t tix = boff + (size_t)ccol * LDW + rrow;
            oth[tix] = h; otl[tix] = lo;
          }
        }
      }
    }
  }
}

extern "C" void kernel_launch(void* const* d_in, const int* in_sizes, int n_in,
                              void* d_out, int out_size, void* d_ws, size_t ws_size,
                              hipStream_t stream) {
  (void)in_sizes; (void)n_in; (void)out_size;
  const float* xin = (const float*)d_in[0];
  const float* coef = (const float*)d_in[1];
  float* xout = (float*)d_out;

  // ws need: 8 bf16 buffers (4 pairs) x CH x 2MB = 16 MB/batch (+64KB slack)
  int CH = 64;
  while (CH > 1 && ((size_t)CH * 16u * 1024u * 1024u + 65536u) > ws_size) CH >>= 1;

  const size_t nE = (size_t)CH << BATCH_SH;
  __hip_bfloat16* P0h = (__hip_bfloat16*)d_ws;
  __hip_bfloat16* P0l = P0h + nE;
  __hip_bfloat16* P1h = P0l + nE;
  __hip_bfloat16* P1l = P1h + nE;
  __hip_bfloat16* P2h = P1l + nE;
  __hip_bfloat16* P2l = P2h + nE;
  __hip_bfloat16* XTh = P2l + nE;
  __hip_bfloat16* XTl = XTh + nE;
  float* partials = (float*)(XTl + nE);
  float* scales = partials + (size_t)CH * 64;

  for (int c = 0; c < 64; c += CH) {
    const float* xi = xin + ((size_t)c << BATCH_SH);
    float* X = xout + ((size_t)c << BATCH_SH);  // final fp32 output only
    k_partial<<<dim3(64, CH), 256, 0, stream>>>(xi, partials);
    k_scale<<<dim3(CH), 64, 0, stream>>>(partials, scales);
    k_scalesplit<<<dim3(16, 16, CH), 256, 0, stream>>>(xi, scales, P0h, P0l, XTh, XTl);

    // rotating pairs: X, A, B  (X_next reuses the dead A pair each iteration)
    __hip_bfloat16 *Xh = P0h, *Xl = P0l, *Ah = P1h, *Al = P1l, *Bh = P2h, *Bl = P2l;
    for (int it = 0; it < 5; ++it) {
      // A = XT * XT^T (symmetric, 10 upper tiles): hi*hi + hi*lo + lo*hi
      k_gemm<1><<<dim3(CH * 10), 512, 0, stream>>>(XTh, XTh, XTl, XTh, XTl, XTh,
                                                   Ah, Al, Ah, Al, nullptr,
                                                   nullptr, nullptr, nullptr);
      // B = c2*A^2 + c1*A + c0*I (symmetric, 10 upper tiles)
      k_gemm<2><<<dim3(CH * 10), 512, 0, stream>>>(Ah, Ah, Al, Ah, Al, Ah,
                                                   Bh, Bl, Bh, Bl, nullptr,
                                                   Ah, Al, coef);
      // X_next = X * B^T (B symmetric); coalesced splits -> dead A pair
      k_gemm<3><<<dim3(CH * 16), 512, 0, stream>>>(Xh, Xh, Xl, Bh, Bl, Bh,
                                                   (it < 4) ? Ah : nullptr,
                                                   (it < 4) ? Al : nullptr,
                                                   nullptr, nullptr,
                                                   (it == 4) ? X : nullptr,
                                                   nullptr, nullptr, nullptr);
      // next-iter XT splits via dedicated coalesced transpose (replaces the
      // scattered column-major stores that dominated xup's epilogue)
      if (it < 4)
        k_transpose<<<dim3(16, 16, CH), 256, 0, stream>>>(
            (const unsigned short*)Ah, (const unsigned short*)Al,
            (unsigned short*)XTh, (unsigned short*)XTl);
      // rotate (X, A, B) <- (A, B, X)
      __hip_bfloat16 *th = Xh, *tl = Xl;
      Xh = Ah; Xl = Al;
      Ah = Bh; Al = Bl;
      Bh = th; Bl = tl;
    }
  }
}

// Round 12
// 7440.285 us; speedup vs baseline: 1.4602x; 1.0063x over previous
//
#include <hip/hip_runtime.h>
#include <hip/hip_bf16.h>
#include <stdint.h>

typedef float f32x4 __attribute__((ext_vector_type(4)));
typedef short bf16x8 __attribute__((ext_vector_type(8)));

#define LDW 1024
#define BATCH_SH 20  // 1<<20 elements per 1024x1024 matrix

__device__ __forceinline__ float b2f(__hip_bfloat16 h) { return __bfloat162float(h); }
__device__ __forceinline__ __hip_bfloat16 f2b(float f) { return __float2bfloat16(f); }

__device__ __forceinline__ void gload16(const void* g, void* l) {
  __builtin_amdgcn_global_load_lds((const __attribute__((address_space(1))) void*)g,
                                   (__attribute__((address_space(3))) void*)l,
                                   16, 0, 0);
}

// ---------------- Frobenius norm partials ----------------
__global__ void k_partial(const float* __restrict__ xin, float* __restrict__ partials) {
  const int b = blockIdx.y, ch = blockIdx.x, t = threadIdx.x;
  const size_t base = ((size_t)b << BATCH_SH) + (size_t)ch * 16384;
  float s = 0.f;
#pragma unroll
  for (int i = 0; i < 16; ++i) {
    f32x4 v = *reinterpret_cast<const f32x4*>(xin + base + (size_t)(i * 256 + t) * 4);
    s += v[0] * v[0] + v[1] * v[1] + v[2] * v[2] + v[3] * v[3];
  }
#pragma unroll
  for (int off = 32; off; off >>= 1) s += __shfl_down(s, off);
  __shared__ float red[4];
  if ((t & 63) == 0) red[t >> 6] = s;
  __syncthreads();
  if (t == 0) partials[b * 64 + ch] = red[0] + red[1] + red[2] + red[3];
}

// ---------------- scale + split + transpose-split (scale folded in) ----------------
__global__ void k_scalesplit(const float* __restrict__ xin, const float* __restrict__ partials,
                             __hip_bfloat16* __restrict__ Xh, __hip_bfloat16* __restrict__ Xl,
                             __hip_bfloat16* __restrict__ XTh, __hip_bfloat16* __restrict__ XTl) {
  __shared__ float tile[64][65];
  const int b = blockIdx.z, tm = blockIdx.y, tn = blockIdx.x;
  const size_t boff = (size_t)b << BATCH_SH;
  const int t = threadIdx.x, lr0 = t >> 6, lc = t & 63;
  // per-wave redundant reduction of the 64 partials (same order as old k_scale)
  float q = partials[b * 64 + (t & 63)];
#pragma unroll
  for (int off = 32; off; off >>= 1) q += __shfl_down(q, off);
  q = __shfl(q, 0);
  const float s = 1.1f / sqrtf(q);
#pragma unroll
  for (int p = 0; p < 16; ++p) {
    const int lr = p * 4 + lr0;
    const size_t idx = boff + (size_t)(tm * 64 + lr) * LDW + tn * 64 + lc;
    const float v = xin[idx] * s;
    __hip_bfloat16 h = f2b(v);
    Xh[idx] = h;
    Xl[idx] = f2b(v - b2f(h));
    tile[lr][lc] = v;
  }
  __syncthreads();
#pragma unroll
  for (int p = 0; p < 16; ++p) {
    const int lr = p * 4 + lr0;
    const float v = tile[lc][lr];
    const size_t idx = boff + (size_t)(tn * 64 + lr) * LDW + tm * 64 + lc;
    __hip_bfloat16 h = f2b(v);
    XTh[idx] = h;
    XTl[idx] = f2b(v - b2f(h));
  }
}

// ---------------- split-bf16 GEMM: C = PA * PB^T, 256x256 tile, BK=64 ----------------
// Effective K = 3072 (3 bf16 segments). 512 threads = 8 waves (2M x 4N).
// Round-7 schedule: 1 raw s_barrier per K-step, global_load_lds staging (linear
// LDS dest + XOR-pre-swizzled global source), vmcnt(0)+lgkmcnt(0) drained once
// per step.
// MODE 1 (SYM):  C symmetric; 10 upper tiles; write splits at (i,j) and (j,i).
// MODE 2 (POLY): v = c2*C + c1*A + c0*I; symmetric writes like MODE 1.
// MODE 3 (XUP):  v = C; if(oh) coalesced splits; if(oth) FUSED LDS-transpose ->
//                coalesced transposed splits (dead staging LDS, 2 half-tiles);
//                if(of) fp32.

#define SEGPTRS(S)                                                                        \
  const int seg_ = (S) >> 4, k0_ = ((S) & 15) << 6;                                       \
  const __hip_bfloat16* pa_ = seg_ == 0 ? pa0 : seg_ == 1 ? pa1 : pa2;                    \
  const __hip_bfloat16* pb_ = seg_ == 0 ? pb0 : seg_ == 1 ? pb1 : pb2;

// lane l of wave w stages row r = it*64 + w*8 + (l>>3), global chunk ((l&7)^(l>>3)),
// into linear LDS slot (row base + l*16). Image: LDS[r][slot] = chunk slot^(r&7).
#define STAGE_GL(DB, S)                                                                   \
  {                                                                                       \
    SEGPTRS(S)                                                                            \
    char* lb_ = smem + (DB) * 65536;                                                      \
    _Pragma("unroll") for (int it_ = 0; it_ < 4; ++it_) {                                 \
      const int r_ = it_ * 64 + w * 8 + (l >> 3);                                         \
      const int kx_ = k0_ + (((l & 7) ^ (l >> 3)) << 3);                                  \
      gload16(pa_ + boff + (size_t)(rowA + r_) * LDW + kx_,                               \
              lb_ + (it_ * 64 + w * 8) * 128 + l * 16);                                   \
      gload16(pb_ + boff + (size_t)(rowB + r_) * LDW + kx_,                               \
              lb_ + 32768 + (it_ * 64 + w * 8) * 128 + l * 16);                           \
    }                                                                                     \
  }

#define MFMA_PHASE(KK, BASE)                                                              \
  {                                                                                       \
    bf16x8 av[8], bv[4];                                                                  \
    _Pragma("unroll") for (int mi_ = 0; mi_ < 8; ++mi_)                                   \
        av[mi_] = *reinterpret_cast<const bf16x8*>(smem + (BASE) + offA[KK][mi_]);        \
    _Pragma("unroll") for (int ni_ = 0; ni_ < 4; ++ni_)                                   \
        bv[ni_] = *reinterpret_cast<const bf16x8*>(smem + (BASE) + offB[KK][ni_]);        \
    __builtin_amdgcn_s_setprio(1);                                                        \
    _Pragma("unroll") for (int mi_ = 0; mi_ < 8; ++mi_)                                   \
        _Pragma("unroll") for (int ni_ = 0; ni_ < 4; ++ni_)                               \
            acc[mi_][ni_] = __builtin_amdgcn_mfma_f32_16x16x32_bf16(                      \
                av[mi_], bv[ni_], acc[mi_][ni_], 0, 0, 0);                                \
    __builtin_amdgcn_s_setprio(0);                                                        \
  }

template <int MODE>
__global__ __launch_bounds__(512, 2) void k_gemm(
    const __hip_bfloat16* __restrict__ pa0, const __hip_bfloat16* __restrict__ pa1,
    const __hip_bfloat16* __restrict__ pa2, const __hip_bfloat16* __restrict__ pb0,
    const __hip_bfloat16* __restrict__ pb1, const __hip_bfloat16* __restrict__ pb2,
    __hip_bfloat16* oh, __hip_bfloat16* ol,
    __hip_bfloat16* oth, __hip_bfloat16* otl,
    float* __restrict__ of,
    const __hip_bfloat16* __restrict__ eh, const __hip_bfloat16* __restrict__ el,
    const float* __restrict__ coef) {
  __shared__ __align__(16) char smem[131072];  // 2 bufs x (A 32KB + B 32KB)
  const int t = threadIdx.x;
  const int w = t >> 6, l = t & 63;
  const int wr = w >> 2, wc = w & 3;  // 2M x 4N wave grid

  // Fully-bijective XCD-aware swizzle (m204): works for any gridDim.x.
  const int nwg = gridDim.x, q = nwg >> 3, r8 = nwg & 7;
  const int xcd = blockIdx.x & 7, o = blockIdx.x >> 3;
  const int wgid = (xcd < r8 ? xcd * (q + 1) : r8 * (q + 1) + (xcd - r8) * q) + o;

  int bat, tm, tn;
  if constexpr (MODE == 3) {
    bat = wgid >> 4;
    const int tile = wgid & 15;
    tm = tile >> 2; tn = tile & 3;
  } else {
    bat = (int)((unsigned)wgid / 10u);
    const int tile = wgid - bat * 10;
    tm = (tile < 4) ? 0 : (tile < 7) ? 1 : (tile < 9) ? 2 : 3;
    tn = (tile < 4) ? tile : (tile < 7) ? (tile - 3) : (tile < 9) ? (tile - 5) : 3;
  }
  const size_t boff = (size_t)bat << BATCH_SH;
  const int rowA = tm * 256, rowB = tn * 256;

  f32x4 acc[8][4];
#pragma unroll
  for (int i = 0; i < 8; ++i)
#pragma unroll
    for (int j = 0; j < 4; ++j) acc[i][j] = (f32x4){0.f, 0.f, 0.f, 0.f};

  // MFMA fragment LDS byte offsets (within a buffer), XOR chunk swizzle
  int offA[2][8], offB[2][4];
#pragma unroll
  for (int kk = 0; kk < 2; ++kk) {
    const int g = kk * 4 + (l >> 4);
#pragma unroll
    for (int mi = 0; mi < 8; ++mi) {
      const int rA = wr * 128 + mi * 16 + (l & 15);
      offA[kk][mi] = rA * 128 + ((g ^ (rA & 7)) << 4);
    }
#pragma unroll
    for (int ni = 0; ni < 4; ++ni) {
      const int rB = wc * 64 + ni * 16 + (l & 15);
      offB[kk][ni] = 32768 + rB * 128 + ((g ^ (rB & 7)) << 4);
    }
  }

  // prologue: stage tile 0 into buf0, drain, converge
  STAGE_GL(0, 0);
  asm volatile("s_waitcnt vmcnt(0)" ::: "memory");
  __builtin_amdgcn_sched_barrier(0);
  __builtin_amdgcn_s_barrier();
  __builtin_amdgcn_sched_barrier(0);

  for (int s = 0; s < 48; ++s) {
    const int base = (s & 1) * 65536;
    if (s + 1 < 48) STAGE_GL((s & 1) ^ 1, s + 1);  // issue early; in flight under MFMA
    __builtin_amdgcn_sched_barrier(0);             // pin issue before compute
    MFMA_PHASE(0, base);
    MFMA_PHASE(1, base);
    // tile s+1 loads retired (issued ~full step ago -> cheap) + my reads done (WAR)
    asm volatile("s_waitcnt vmcnt(0) lgkmcnt(0)" ::: "memory");
    __builtin_amdgcn_sched_barrier(0);
    __builtin_amdgcn_s_barrier();
    __builtin_amdgcn_sched_barrier(0);
  }

  float c0 = 0.f, c1 = 0.f, c2 = 0.f;
  if constexpr (MODE == 2) { c0 = coef[0]; c1 = coef[1]; c2 = coef[2]; }
  const int r0 = tm * 256 + wr * 128 + ((l >> 4) << 2);
  const int cb = tn * 256 + wc * 64 + (l & 15);
#pragma unroll
  for (int mi = 0; mi < 8; ++mi) {
#pragma unroll
    for (int ni = 0; ni < 4; ++ni) {
      const int ccol = cb + ni * 16;
#pragma unroll
      for (int j = 0; j < 4; ++j) {
        const int rrow = r0 + mi * 16 + j;
        const size_t idx = boff + (size_t)rrow * LDW + ccol;
        float v = acc[mi][ni][j];
        if constexpr (MODE == 2)
          v = c2 * v + c1 * (b2f(eh[idx]) + b2f(el[idx])) + (rrow == ccol ? c0 : 0.f);
        __hip_bfloat16 h = f2b(v);
        __hip_bfloat16 lo = f2b(v - b2f(h));
        if constexpr (MODE == 3) {
          if (oh) { oh[idx] = h; ol[idx] = lo; }
          if (of) of[idx] = v;
        } else {
          oh[idx] = h; ol[idx] = lo;
          if (tm != tn) {
            const size_t tix = boff + (size_t)ccol * LDW + rrow;
            oth[tix] = h; otl[tix] = lo;
          }
        }
      }
    }
  }

  // ---- MODE 3 fused transpose: dead staging LDS = one 256x128 u32 half-tile ----
  if constexpr (MODE == 3) {
    if (oth) {
      unsigned* tlds = reinterpret_cast<unsigned*>(smem);
      unsigned short* pth = reinterpret_cast<unsigned short*>(oth);
      unsigned short* ptl = reinterpret_cast<unsigned short*>(otl);
#pragma unroll
      for (int h2 = 0; h2 < 2; ++h2) {
        __builtin_amdgcn_s_barrier();  // K-loop reads / previous half reads done
        if ((wc >> 1) == h2) {         // waves owning this 128-col half pack into LDS
#pragma unroll
          for (int mi = 0; mi < 8; ++mi) {
#pragma unroll
            for (int ni = 0; ni < 4; ++ni) {
              const int cl = (wc & 1) * 64 + ni * 16 + (l & 15);  // 0..127 in half
#pragma unroll
              for (int j = 0; j < 4; ++j) {
                const int rr = wr * 128 + ((l >> 4) << 2) + mi * 16 + j;  // 0..255
                const float v = acc[mi][ni][j];
                const __hip_bfloat16 hh = f2b(v);
                const __hip_bfloat16 lo = f2b(v - b2f(hh));
                const unsigned pk = (unsigned)(*(const unsigned short*)&hh) |
                                    ((unsigned)(*(const unsigned short*)&lo) << 16);
                tlds[rr * 128 + (cl ^ ((rr >> 1) & 31))] = pk;
              }
            }
          }
        }
        __builtin_amdgcn_s_barrier();
        // all 8 waves: emit 16 transposed rows each, u32-packed coalesced stores
#pragma unroll
        for (int i = 0; i < 16; ++i) {
          const int trow = w * 16 + i;  // 0..127 within this half
          const size_t obase =
              boff + (size_t)(tn * 256 + h2 * 128 + trow) * LDW + tm * 256;
#pragma unroll
          for (int c = 0; c < 2; ++c) {
            const int e0 = (c * 64 + l) * 2;  // even element index 0..254
            const int m = (e0 >> 1) & 31;     // same mask for e0 and e0+1
            const unsigned p0 = tlds[e0 * 128 + (trow ^ m)];
            const unsigned p1 = tlds[(e0 + 1) * 128 + (trow ^ m)];
            *reinterpret_cast<unsigned*>(pth + obase + e0) =
                (p0 & 0xffffu) | (p1 << 16);
            *reinterpret_cast<unsigned*>(ptl + obase + e0) =
                (p0 >> 16) | (p1 & 0xffff0000u);
          }
        }
      }
    }
  }
}

extern "C" void kernel_launch(void* const* d_in, const int* in_sizes, int n_in,
                              void* d_out, int out_size, void* d_ws, size_t ws_size,
                              hipStream_t stream) {
  (void)in_sizes; (void)n_in; (void)out_size;
  const float* xin = (const float*)d_in[0];
  const float* coef = (const float*)d_in[1];
  float* xout = (float*)d_out;

  // ws need: 8 bf16 buffers (4 pairs) x CH x 2MB = 16 MB/batch (+64KB slack)
  int CH = 64;
  while (CH > 1 && ((size_t)CH * 16u * 1024u * 1024u + 65536u) > ws_size) CH >>= 1;

  const size_t nE = (size_t)CH << BATCH_SH;
  __hip_bfloat16* P0h = (__hip_bfloat16*)d_ws;
  __hip_bfloat16* P0l = P0h + nE;
  __hip_bfloat16* P1h = P0l + nE;
  __hip_bfloat16* P1l = P1h + nE;
  __hip_bfloat16* P2h = P1l + nE;
  __hip_bfloat16* P2l = P2h + nE;
  __hip_bfloat16* XTh = P2l + nE;
  __hip_bfloat16* XTl = XTh + nE;
  float* partials = (float*)(XTl + nE);

  for (int c = 0; c < 64; c += CH) {
    const float* xi = xin + ((size_t)c << BATCH_SH);
    float* X = xout + ((size_t)c << BATCH_SH);  // final fp32 output only
    k_partial<<<dim3(64, CH), 256, 0, stream>>>(xi, partials);
    k_scalesplit<<<dim3(16, 16, CH), 256, 0, stream>>>(xi, partials, P0h, P0l, XTh, XTl);

    // rotating pairs: X, A, B  (X_next reuses the dead A pair each iteration)
    __hip_bfloat16 *Xh = P0h, *Xl = P0l, *Ah = P1h, *Al = P1l, *Bh = P2h, *Bl = P2l;
    for (int it = 0; it < 5; ++it) {
      // A = XT * XT^T (symmetric, 10 upper tiles): hi*hi + hi*lo + lo*hi
      k_gemm<1><<<dim3(CH * 10), 512, 0, stream>>>(XTh, XTh, XTl, XTh, XTl, XTh,
                                                   Ah, Al, Ah, Al, nullptr,
                                                   nullptr, nullptr, nullptr);
      // B = c2*A^2 + c1*A + c0*I (symmetric, 10 upper tiles)
      k_gemm<2><<<dim3(CH * 10), 512, 0, stream>>>(Ah, Ah, Al, Ah, Al, Ah,
                                                   Bh, Bl, Bh, Bl, nullptr,
                                                   Ah, Al, coef);
      // X_next = X * B^T (B symmetric); coalesced splits -> dead A pair;
      // XT splits fused via LDS transpose (it<4); fp32 out on last iter.
      k_gemm<3><<<dim3(CH * 16), 512, 0, stream>>>(Xh, Xh, Xl, Bh, Bl, Bh,
                                                   (it < 4) ? Ah : nullptr,
                                                   (it < 4) ? Al : nullptr,
                                                   (it < 4) ? XTh : nullptr,
                                                   (it < 4) ? XTl : nullptr,
                                                   (it == 4) ? X : nullptr,
                                                   nullptr, nullptr, nullptr);
      // rotate (X, A, B) <- (A, B, X)
      __hip_bfloat16 *th = Xh, *tl = Xl;
      Xh = Ah; Xl = Al;
      Ah = Bh; Al = Bl;
      Bh = th; Bl = tl;
    }
  }
}